// Round 1
// baseline (93.504 us; speedup 1.0000x reference)
//
#include <hip/hip_runtime.h>

#define BATCH 8192
#define V 128
#define H 512
#define NET_W (2 * V)   // 256

// Kernel A: one block per idx0 value (128 blocks, 256 threads).
// Computes net = relu(W1[idx0,:] + b1) @ W2 + b2  (256 wide), then
// argmax of net[0:128] -> loc_idx[idx0], argmax of net[128:256] -> scale_idx[idx0].
__global__ void precompute_argmax_kernel(const float* __restrict__ W1,
                                         const float* __restrict__ b1,
                                         const float* __restrict__ W2,
                                         const float* __restrict__ b2,
                                         int* __restrict__ loc_idx,
                                         int* __restrict__ scale_idx) {
    __shared__ float h[H];
    __shared__ float net[NET_W];
    const int row = blockIdx.x;   // idx0 in [0,128)
    const int t   = threadIdx.x;  // 0..255

    // h[j] = relu(W1[row, j] + b1[j]), j in [0,512)
    for (int j = t; j < H; j += 256) {
        float v = W1[row * H + j] + b1[j];
        h[j] = v > 0.0f ? v : 0.0f;
    }
    __syncthreads();

    // net[t] = sum_j h[j] * W2[j, t] + b2[t]   (W2 row-major (512, 256): coalesced)
    float acc = b2[t];
#pragma unroll 8
    for (int j = 0; j < H; ++j) {
        acc = fmaf(h[j], W2[j * NET_W + t], acc);
    }
    net[t] = acc;
    __syncthreads();

    // First-occurrence argmax (matches jnp.argmax tie-break: strict >).
    if (t == 0) {
        float best = net[0]; int bi = 0;
        for (int c = 1; c < V; ++c) {
            if (net[c] > best) { best = net[c]; bi = c; }
        }
        loc_idx[row] = bi;
    } else if (t == 64) {
        float best = net[V]; int bi = 0;
        for (int c = 1; c < V; ++c) {
            if (net[V + c] > best) { best = net[V + c]; bi = c; }
        }
        scale_idx[row] = bi;
    }
}

// Kernel B: one block per batch row (8192 blocks, 256 threads).
// out[b, 0:128]   = x0 row (copy)
// out[b, 128:256] = one-hot at (a*s + l) & 127, or zeros if s == 0
__global__ void flow_kernel(const float* __restrict__ inputs,
                            const int* __restrict__ loc_idx,
                            const int* __restrict__ scale_idx,
                            float* __restrict__ out) {
    const int b = blockIdx.x;
    const int t = threadIdx.x;  // 0..255
    __shared__ int s_idx0;
    __shared__ int s_a;

    const float v = inputs[b * NET_W + t];
    if (v > 0.5f) {
        if (t < V) s_idx0 = t;
        else       s_a    = t - V;
    }
    __syncthreads();

    float o;
    if (t < V) {
        o = v;  // copy x0
    } else {
        const int l = loc_idx[s_idx0];
        const int s = scale_idx[s_idx0];
        const int c = t - V;
        const int zc = (s_a * s + l) & (V - 1);
        o = (s != 0 && c == zc) ? 1.0f : 0.0f;
    }
    out[b * NET_W + t] = o;
}

extern "C" void kernel_launch(void* const* d_in, const int* in_sizes, int n_in,
                              void* d_out, int out_size, void* d_ws, size_t ws_size,
                              hipStream_t stream) {
    const float* inputs = (const float*)d_in[0];  // (8192, 256)
    const float* W1     = (const float*)d_in[1];  // (128, 512)
    const float* b1     = (const float*)d_in[2];  // (512,)
    const float* W2     = (const float*)d_in[3];  // (512, 256)
    const float* b2     = (const float*)d_in[4];  // (256,)
    float* out = (float*)d_out;                   // (8192, 256)

    int* loc_idx   = (int*)d_ws;        // 128 ints
    int* scale_idx = loc_idx + V;       // 128 ints

    precompute_argmax_kernel<<<V, 256, 0, stream>>>(W1, b1, W2, b2, loc_idx, scale_idx);
    flow_kernel<<<BATCH, 256, 0, stream>>>(inputs, loc_idx, scale_idx, out);
}

// Round 3
// 77.039 us; speedup vs baseline: 1.2137x; 1.2137x over previous
//
#include <hip/hip_runtime.h>

#define BATCH 8192
#define V 128
#define H 512
#define NET_W (2 * V)   // 256

// Kernel A: one block per (idx0 row, output half). 256 blocks x 512 threads.
//   half 0 -> net[0:128]  -> loc_idx[row]
//   half 1 -> net[128:256]-> scale_idx[row]
// Parallel GEMM (4-way K-split per column), then serial thread-0 argmax
// (first-occurrence tie-break, matches jnp.argmax). No shuffles, no
// data-dependent indexing — cannot fault.
__global__ __launch_bounds__(512) void precompute_argmax_kernel(
        const float* __restrict__ W1,
        const float* __restrict__ b1,
        const float* __restrict__ W2,
        const float* __restrict__ b2,
        int* __restrict__ loc_idx,
        int* __restrict__ scale_idx) {
    __shared__ float h[H];
    __shared__ float part[4][V];
    __shared__ float net[V];

    const int row  = blockIdx.x >> 1;
    const int half = blockIdx.x & 1;
    const int t    = threadIdx.x;          // 0..511
    const int c    = t & (V - 1);          // column within half: 0..127
    const int k    = t >> 7;               // K-chunk: 0..3

    // h[j] = relu(W1[row, j] + b1[j])
    {
        float v = W1[row * H + t] + b1[t];
        h[t] = v > 0.0f ? v : 0.0f;
    }
    __syncthreads();

    // Partial dot over j in [k*128, (k+1)*128), output column = half*128 + c.
    const float* __restrict__ w2p = W2 + (size_t)(k * 128) * NET_W + half * V + c;
    const float* __restrict__ hp  = h + k * 128;
    float acc = 0.0f;
#pragma unroll 8
    for (int j = 0; j < 128; ++j) {
        acc = fmaf(hp[j], w2p[(size_t)j * NET_W], acc);
    }
    part[k][c] = acc;
    __syncthreads();

    if (t < V) {
        net[t] = part[0][t] + part[1][t] + part[2][t] + part[3][t] + b2[half * V + t];
    }
    __syncthreads();

    if (t == 0) {
        float best = net[0]; int bi = 0;
        for (int i = 1; i < V; ++i) {
            if (net[i] > best) { best = net[i]; bi = i; }
        }
        if (half == 0) loc_idx[row] = bi;
        else           scale_idx[row] = bi;
    }
}

// Kernel B: one wave per batch row, 4 rows per 256-thread block, float4 I/O.
// Index discovery via LDS broadcast (proven in R1); all data-dependent
// indices masked to [0,128) so no path can read OOB.
__global__ __launch_bounds__(256) void flow_kernel(
        const float* __restrict__ inputs,
        const int* __restrict__ loc_idx,
        const int* __restrict__ scale_idx,
        float* __restrict__ out) {
    __shared__ int s_idx0[4];
    __shared__ int s_a[4];

    const int tid  = threadIdx.x;
    const int wid  = tid >> 6;    // row slot within block: 0..3
    const int lane = tid & 63;
    const int b    = blockIdx.x * 4 + wid;

    // Lane i holds row elements [4i, 4i+4): lanes 0..31 = x0, 32..63 = x1.
    const float4 v = ((const float4*)inputs)[(size_t)b * 64 + lane];

    const int local = (v.x > 0.5f) ? 0 :
                      (v.y > 0.5f) ? 1 :
                      (v.z > 0.5f) ? 2 :
                      (v.w > 0.5f) ? 3 : -1;
    if (local >= 0) {
        const int pos = lane * 4 + local;          // hot column in [0,256)
        if (pos < V) s_idx0[wid] = pos;            // argwhere(x0)
        else         s_a[wid]    = pos - V;        // argwhere(x1)
    }
    __syncthreads();

    const int idx0 = s_idx0[wid] & (V - 1);
    const int a    = s_a[wid]    & (V - 1);
    const int l    = loc_idx[idx0];
    const int s    = scale_idx[idx0];
    const int zc   = (a * s + l) & (V - 1);        // target col within z1
    const int hot  = (s != 0) ? (V + zc) : -1;     // col within full 256-row

    float4 o;
    if (lane < 32) {
        o = v;  // copy x0 verbatim
    } else {
        const int c0 = lane * 4;
        o.x = (c0 + 0 == hot) ? 1.0f : 0.0f;
        o.y = (c0 + 1 == hot) ? 1.0f : 0.0f;
        o.z = (c0 + 2 == hot) ? 1.0f : 0.0f;
        o.w = (c0 + 3 == hot) ? 1.0f : 0.0f;
    }
    ((float4*)out)[(size_t)b * 64 + lane] = o;
}

extern "C" void kernel_launch(void* const* d_in, const int* in_sizes, int n_in,
                              void* d_out, int out_size, void* d_ws, size_t ws_size,
                              hipStream_t stream) {
    const float* inputs = (const float*)d_in[0];  // (8192, 256)
    const float* W1     = (const float*)d_in[1];  // (128, 512)
    const float* b1     = (const float*)d_in[2];  // (512,)
    const float* W2     = (const float*)d_in[3];  // (512, 256)
    const float* b2     = (const float*)d_in[4];  // (256,)
    float* out = (float*)d_out;                   // (8192, 256)

    int* loc_idx   = (int*)d_ws;        // 128 ints
    int* scale_idx = loc_idx + V;       // 128 ints

    precompute_argmax_kernel<<<2 * V, 512, 0, stream>>>(W1, b1, W2, b2, loc_idx, scale_idx);
    flow_kernel<<<BATCH / 4, 256, 0, stream>>>(inputs, loc_idx, scale_idx, out);
}